// Round 5
// baseline (131.955 us; speedup 1.0000x reference)
//
#include <hip/hip_runtime.h>
#include <math.h>

#define KBINS 16
#define HID 16
// ln(0.02)
#define LN_SIGMA1 (-3.912023005428146f)
#define LOG2E 1.4426950408889634f

// Native 16B vector type for 128-bit global stores.
typedef float floatx4 __attribute__((ext_vector_type(4)));

// Force a wave-uniform value into an SGPR (weights are uniform per block).
__device__ __forceinline__ float to_sgpr(float x) {
    return __int_as_float(__builtin_amdgcn_readfirstlane(__float_as_int(x)));
}

// R5 ablation: NO LDS, NO __syncthreads. Each thread stores its element's
// 64 B directly (4x dwordx4 at 64 B lane stride; a wave's 4 store instrs
// fully cover every 128 B line -> L2 merges to full lines). Tests whether
// the staged-epilogue (LDS roundtrip + barrier + bursty stores) was the
// kernel's cost center. Occupancy stays 8 waves/SIMD (<=64 VGPR, 0 LDS).
__global__ __launch_bounds__(256, 8) void bfn_kernel(
    const float* __restrict__ mu,
    const float* __restrict__ t,
    const float* __restrict__ W1,   // [2,16]
    const float* __restrict__ b1,   // [16]
    const float* __restrict__ W2,   // [16,2]
    const float* __restrict__ b2,   // [2]
    float* __restrict__ out,        // [B,D,16]
    int D)
{
    const int b   = blockIdx.y;
    const int tid = threadIdx.x;
    const int d0  = blockIdx.x * 256;
    const int d   = d0 + tid;
    const bool valid = (d < D);

    // mu load issued first; latency overlaps the uniform prologue.
    const float m = valid ? mu[(size_t)b * D + d] : 0.0f;

    // ---- wave-uniform per-row constants ----
    const float tb    = t[b];
    const float gamma = -expm1f(2.0f * tb * LN_SIGMA1);  // 1 - 0.02^(2t)
    const float e2t   = 1.0f - gamma;                    // 0.02^(2t)
    const float inv_gamma = to_sgpr(1.0f / gamma);
    const float var_scale = to_sgpr(sqrtf(e2t * inv_gamma));
    const bool  tiny_t = (tb < 1e-6f);

    // All weights to SGPRs (c1 = tb*W1[1]+b1 is uniform too).
    float w1a[HID], c1[HID], w20[HID], w21[HID];
#pragma unroll
    for (int i = 0; i < HID; ++i) {
        w1a[i] = to_sgpr(W1[i]);
        c1[i]  = to_sgpr(fmaf(tb, W1[HID + i], b1[i]));
        w20[i] = to_sgpr(W2[2 * i]);
        w21[i] = to_sgpr(W2[2 * i + 1]);
    }
    const float bias0 = to_sgpr(b2[0]);
    const float bias1 = to_sgpr(b2[1]);

    // ---- MLP: gelu(tanh approx) == pre * sigmoid(2u), exp2 with log2e
    // folded into the polynomial coefficients.
    float o0 = bias0, o1 = bias1;
#pragma unroll
    for (int i = 0; i < HID; ++i) {
        float pre = fmaf(m, w1a[i], c1[i]);
        float p2  = pre * pre;
        float z2  = pre * fmaf(p2, -0.1029440437f, -2.3022081926f);  // -2u*log2e
        float e   = __builtin_amdgcn_exp2f(z2);
        float h   = pre * __builtin_amdgcn_rcpf(1.0f + e);
        o0 = fmaf(h, w20[i], o0);
        o1 = fmaf(h, w21[i], o1);
    }

    float mu_x = fmaf(m, inv_gamma, -var_scale * o0);
    float lse  = fminf(fmaxf(o1, -10.0f), 10.0f);
    float sigma_x = fmaxf(var_scale * __builtin_amdgcn_exp2f(lse * LOG2E), 0.02f);
    if (tiny_t) { mu_x = 0.0f; sigma_x = 1.0f; }   // wave-uniform branch

    const float inv = 0.70710678118f * __builtin_amdgcn_rcpf(sigma_x);
    const float x0  = (-0.875f - mu_x) * inv;   // boundary j=1
    const float stp = 0.125f * inv;

    // cdf at boundaries 1..15 (0 and 16 exact 0/1), rolling difference,
    // each float4 stored straight to global as it completes.
    // erf via A&S 7.1.27: erf(|x|) ~= 1 - q^-4, |err|<=5e-4; saturates
    // through rcp(inf)=0.
    floatx4* op = (floatx4*)(out) + (size_t)(b * (size_t)D + d) * 4;
    float prev = 0.0f;
#pragma unroll
    for (int s = 0; s < 4; ++s) {
        float v[4];
#pragma unroll
        for (int q = 0; q < 4; ++q) {
            const int j = 4 * s + q + 1;
            float cur;
            if (j == KBINS) {
                cur = 1.0f;
            } else {
                float x  = fmaf((float)(j - 1), stp, x0);
                float ax = fabsf(x);
                float p  = fmaf(0.078108f, ax, 0.000972f);
                p        = fmaf(p, ax, 0.230389f);
                p        = fmaf(p, ax, 0.278393f);
                float qq = fmaf(p, ax, 1.0f);
                float q2 = qq * qq;
                float q4 = q2 * q2;
                float hr = 0.5f * __builtin_amdgcn_rcpf(q4);
                cur = (x >= 0.0f) ? (1.0f - hr) : hr;
            }
            v[q] = cur - prev;
            prev = cur;
        }
        if (valid) {
            floatx4 rr = { v[0], v[1], v[2], v[3] };
            op[s] = rr;
        }
    }
}

extern "C" void kernel_launch(void* const* d_in, const int* in_sizes, int n_in,
                              void* d_out, int out_size, void* d_ws, size_t ws_size,
                              hipStream_t stream) {
    const float* mu = (const float*)d_in[0];
    const float* t  = (const float*)d_in[1];
    const float* W1 = (const float*)d_in[2];
    const float* b1 = (const float*)d_in[3];
    const float* W2 = (const float*)d_in[4];
    const float* b2 = (const float*)d_in[5];
    float* out = (float*)d_out;

    const int B = in_sizes[1];          // t is [B,1]
    const int D = in_sizes[0] / B;      // mu is [B,D]

    dim3 block(256);
    dim3 grid((D + 255) / 256, B);
    bfn_kernel<<<grid, block, 0, stream>>>(mu, t, W1, b1, W2, b2, out, D);
}

// Round 6
// 122.405 us; speedup vs baseline: 1.0780x; 1.0780x over previous
//
#include <hip/hip_runtime.h>
#include <math.h>

#define KBINS 16
#define HID 16
// ln(0.02)
#define LN_SIGMA1 (-3.912023005428146f)

// Force a wave-uniform value into an SGPR (weights are uniform per block).
__device__ __forceinline__ float to_sgpr(float x) {
    return __int_as_float(__builtin_amdgcn_readfirstlane(__float_as_int(x)));
}

__global__ __launch_bounds__(256, 4) void bfn_kernel(
    const float* __restrict__ mu,
    const float* __restrict__ t,
    const float* __restrict__ W1,   // [2,16]
    const float* __restrict__ b1,   // [16]
    const float* __restrict__ W2,   // [16,2]
    const float* __restrict__ b2,   // [2]
    float* __restrict__ out,        // [B,D,16]
    int D)
{
    // 256 rows x 20 words (80 B row stride: 16B-aligned, conflict-free for
    // both the b128 writes and the strided b128 transpose reads).
    __shared__ float lds[256 * 20];

    const int b   = blockIdx.y;
    const int tid = threadIdx.x;
    const int d0  = blockIdx.x * 256;
    const int d   = d0 + tid;
    const bool valid = (d < D);

    // ---- wave-uniform per-row constants ----
    const float tb    = t[b];
    const float gamma = -expm1f(2.0f * tb * LN_SIGMA1);  // 1 - 0.02^(2t), no cancellation
    const float e2t   = 1.0f - gamma;                    // 0.02^(2t)
    const float inv_gamma = 1.0f / gamma;
    const float var_scale = sqrtf(e2t * inv_gamma);
    const bool  tiny_t = (tb < 1e-6f);

    // weights -> SGPRs (uniform); c1 = t*W1[1]+b1 stays VGPR (1 SGPR/VALU rule)
    float w1a[HID], c1[HID], w20[HID], w21[HID];
#pragma unroll
    for (int i = 0; i < HID; ++i) {
        w1a[i] = to_sgpr(W1[i]);
        c1[i]  = fmaf(tb, W1[HID + i], b1[i]);
        w20[i] = to_sgpr(W2[2 * i]);
        w21[i] = to_sgpr(W2[2 * i + 1]);
    }
    const float bias0 = to_sgpr(b2[0]);
    const float bias1 = to_sgpr(b2[1]);

    const float m = valid ? mu[(size_t)b * D + d] : 0.0f;

    // ---- MLP: gelu(tanh approx) == pre * sigmoid(2u), u = 0.79788456*(pre + 0.044715 pre^3)
    float o0 = bias0, o1 = bias1;
#pragma unroll
    for (int i = 0; i < HID; ++i) {
        float pre = fmaf(m, w1a[i], c1[i]);
        float p2  = pre * pre;
        float z   = pre * fmaf(p2, -0.0713552235f, -1.5957691216f);  // -2u
        float e   = __expf(z);
        float h   = pre * __builtin_amdgcn_rcpf(1.0f + e);
        o0 = fmaf(h, w20[i], o0);
        o1 = fmaf(h, w21[i], o1);
    }

    float mu_x = fmaf(m, inv_gamma, -var_scale * o0);
    float lse  = fminf(fmaxf(o1, -10.0f), 10.0f);
    float sigma_x = fmaxf(var_scale * __expf(lse), 0.02f);
    if (tiny_t) { mu_x = 0.0f; sigma_x = 1.0f; }

    const float inv = 0.70710678118f * __builtin_amdgcn_rcpf(sigma_x);
    const float x0  = (-0.875f - mu_x) * inv;   // boundary j=1
    const float stp = 0.125f * inv;

    // cdf at 17 boundaries; 0 and 16 are exact 0/1. erf via A&S 7.1.27:
    // erf(|x|) ~= 1 - q^-4, q = 1 + a1|x| + a2 x^2 + a3 |x|^3 + a4 x^4  (|err|<=5e-4)
    // cdf = x>=0 ? 1 - r/2 : r/2, r = rcp(q^4); saturates via rcp(inf)=0.
    float cdf[KBINS + 1];
    cdf[0] = 0.0f; cdf[KBINS] = 1.0f;
#pragma unroll
    for (int j = 1; j < KBINS; ++j) {
        float x  = fmaf((float)(j - 1), stp, x0);
        float ax = fabsf(x);
        float p  = fmaf(0.078108f, ax, 0.000972f);
        p        = fmaf(p, ax, 0.230389f);
        p        = fmaf(p, ax, 0.278393f);
        float q  = fmaf(p, ax, 1.0f);
        float q2 = q * q;
        float q4 = q2 * q2;
        float hr = 0.5f * __builtin_amdgcn_rcpf(q4);
        cdf[j] = (x >= 0.0f) ? (1.0f - hr) : hr;
    }

    const bool full = (d0 + 256 <= D);   // D=49152 -> always true; tail path for safety
    if (full) {
        // stage per-element rows in LDS, then write block's 16 KB coalesced
        float4* row = (float4*)(lds + tid * 20);
#pragma unroll
        for (int s = 0; s < 4; ++s)
            row[s] = make_float4(cdf[4*s+1] - cdf[4*s],   cdf[4*s+2] - cdf[4*s+1],
                                 cdf[4*s+3] - cdf[4*s+2], cdf[4*s+4] - cdf[4*s+3]);
        __syncthreads();
        float4* og = (float4*)out + ((size_t)b * D + d0) * 4;
#pragma unroll
        for (int s = 0; s < 4; ++s) {
            int f = s * 256 + tid;          // block-local float4 index, coalesced
            int e = f >> 2;                 // source element row
            int c = (f & 3) << 2;           // word offset in row
            og[f] = *(const float4*)(lds + e * 20 + c);
        }
    } else if (valid) {
        float4* op = (float4*)(out + ((size_t)b * D + d) * (size_t)KBINS);
#pragma unroll
        for (int s = 0; s < 4; ++s)
            op[s] = make_float4(cdf[4*s+1] - cdf[4*s],   cdf[4*s+2] - cdf[4*s+1],
                                 cdf[4*s+3] - cdf[4*s+2], cdf[4*s+4] - cdf[4*s+3]);
    }
}

extern "C" void kernel_launch(void* const* d_in, const int* in_sizes, int n_in,
                              void* d_out, int out_size, void* d_ws, size_t ws_size,
                              hipStream_t stream) {
    const float* mu = (const float*)d_in[0];
    const float* t  = (const float*)d_in[1];
    const float* W1 = (const float*)d_in[2];
    const float* b1 = (const float*)d_in[3];
    const float* W2 = (const float*)d_in[4];
    const float* b2 = (const float*)d_in[5];
    float* out = (float*)d_out;

    const int B = in_sizes[1];          // t is [B,1]
    const int D = in_sizes[0] / B;      // mu is [B,D]

    dim3 block(256);
    dim3 grid((D + 255) / 256, B);
    bfn_kernel<<<grid, block, 0, stream>>>(mu, t, W1, b1, W2, b2, out, D);
}